// Round 13
// baseline (39.883 us; speedup 1.0000x reference)
//
#include <hip/hip_runtime.h>
#include <hip/hip_bf16.h>

#define SPATIAL_SCALE 0.0625f
#define POOLED 7
#define NBIN 49
#define PARTS 7
#define SAMPLES 4
#define NSAMP 16
#define TRANS_STD 0.1f

#define BB 2
#define CC 128
#define HH 128
#define WW 128
#define HWC (HH * WW * CC)    // elements

#define WIN 5        // max window extent per axis (3*sub_w <= 2.91)
#define MAXP 32      // 25 cells padded
#define NKEY 128     // BB * 8 * 8 spatial-cell keys
#define NBMAX 28     // bins in half 0 (ph 0..3); half 1 has 21
#define NBP 29       // padded s_res row stride

// native clang vectors for nontemporal builtins
typedef float  nfloat4  __attribute__((ext_vector_type(4)));
typedef unsigned short nushort4 __attribute__((ext_vector_type(4)));

// ---------------- fused: transpose (B,C,H,W)f32 -> (B,H,W,C)bf16  +  csort ----------------
// nt loads (read-once source, don't thrash L2) + nt stores (featT lands in
// LLC clean -> pool's first-touch misses are clean LLC fills, not cross-XCD
// dirty-line services).
__global__ __launch_bounds__(256) void transpose_csort(
        const float* __restrict__ in, __hip_bfloat16* __restrict__ out,
        const float* __restrict__ rois, int N, int* __restrict__ perm) {
    __shared__ float tile[128][129];
    __shared__ int hist[NKEY];
    __shared__ int scan[NKEY];
    __shared__ int pos[NKEY];

    int tid = threadIdx.x;
    int bx = blockIdx.x;
    int by = blockIdx.y;

    if (bx == 0 && by == 0) {
        if (tid < NKEY) hist[tid] = 0;
        __syncthreads();
        for (int i = tid; i < N; i += 256) {
            float b  = rois[i * 5 + 0];
            float x1 = rois[i * 5 + 1];
            float y1 = rois[i * 5 + 2];
            float x2 = rois[i * 5 + 3];
            float y2 = rois[i * 5 + 4];
            float fx = (x1 + x2) * 0.5f * SPATIAL_SCALE;
            float fy = (y1 + y2) * 0.5f * SPATIAL_SCALE;
            int cx = min(7, max(0, (int)(fx * 0.0625f)));
            int cy = min(7, max(0, (int)(fy * 0.0625f)));
            atomicAdd(&hist[((int)b * 8 + cy) * 8 + cx], 1);
        }
        __syncthreads();
        if (tid < NKEY) scan[tid] = hist[tid];
        __syncthreads();
        #pragma unroll
        for (int s = 1; s < NKEY; s <<= 1) {
            int v = 0;
            if (tid < NKEY && tid >= s) v = scan[tid - s];
            __syncthreads();
            if (tid < NKEY) scan[tid] += v;
            __syncthreads();
        }
        if (tid < NKEY) pos[tid] = scan[tid] - hist[tid];
        __syncthreads();
        for (int i = tid; i < N; i += 256) {
            float b  = rois[i * 5 + 0];
            float x1 = rois[i * 5 + 1];
            float y1 = rois[i * 5 + 2];
            float x2 = rois[i * 5 + 3];
            float y2 = rois[i * 5 + 4];
            float fx = (x1 + x2) * 0.5f * SPATIAL_SCALE;
            float fy = (y1 + y2) * 0.5f * SPATIAL_SCALE;
            int cx = min(7, max(0, (int)(fx * 0.0625f)));
            int cy = min(7, max(0, (int)(fy * 0.0625f)));
            int key = ((int)b * 8 + cy) * 8 + cx;
            int slot = atomicAdd(&pos[key], 1);
            perm[slot] = i;
        }
        __syncthreads();
    }

    const int HW = HH * WW;
    size_t base = (size_t)by * CC * HW;
    int p0 = bx * 128;

    #pragma unroll
    for (int it = 0; it < 16; ++it) {
        int i = tid + it * 256;
        int c = i >> 5;
        int q = i & 31;
        const nfloat4* sp =
            (const nfloat4*)(in + base + (size_t)c * HW + p0 + 4 * q);
        nfloat4 v = __builtin_nontemporal_load(sp);
        int p = 4 * q;
        tile[p + 0][c] = v.x;
        tile[p + 1][c] = v.y;
        tile[p + 2][c] = v.z;
        tile[p + 3][c] = v.w;
    }
    __syncthreads();

    __hip_bfloat16* dst = out + base + (size_t)p0 * CC;
    #pragma unroll
    for (int it = 0; it < 16; ++it) {
        int i = tid + it * 256;
        int p = i >> 5;
        int m = i & 31;
        union { nushort4 u4; __hip_bfloat16 h[4]; } pk;
        pk.h[0] = __float2bfloat16(tile[p][4 * m + 0]);
        pk.h[1] = __float2bfloat16(tile[p][4 * m + 1]);
        pk.h[2] = __float2bfloat16(tile[p][4 * m + 2]);
        pk.h[3] = __float2bfloat16(tile[p][4 * m + 3]);
        __builtin_nontemporal_store(pk.u4,
            (nushort4*)(dst + (size_t)p * CC + 4 * m));
    }
}

// ---------------- half-ROI per block, r8-style VGPR-lean paired gather ----------------
// 1024 blocks; LDS ~25KB, VGPR ~40 -> 4 blocks/CU = 32 waves/CU (full occupancy).
__global__ __launch_bounds__(512) void dpsroi_half(
        const __hip_bfloat16* __restrict__ feat,   // (B,H,W,C) bf16
        const float* __restrict__ rois,
        const float* __restrict__ offset,
        const int* __restrict__ perm,
        float* __restrict__ out,                   // (N, C, 7, 7) f32
        int N) {
    __shared__ float s_w[NBMAX][WIN * WIN];
    __shared__ int2  s_ow[NBMAX][MAXP];
    __shared__ int   s_rc[NBMAX];
    __shared__ float s_res[CC * NBP];              // [c][NBP]

    int tid  = threadIdx.x;
    int lane = tid & 63;
    int wv   = tid >> 6;

    // bijective XCD chunk swizzle over 2N blocks
    int nwg = gridDim.x;
    int q = nwg >> 3, r = nwg & 7;
    int xcd = blockIdx.x & 7;
    int idx = blockIdx.x >> 3;
    int wg = (xcd < r ? xcd * (q + 1) : r * (q + 1) + (xcd - r) * q) + idx;
    int half = wg & 1;
    int n = perm[wg >> 1];
    int binbase = half * 28;
    int NB = half ? 21 : 28;

    float R0 = rois[n * 5 + 0];
    float R1 = rois[n * 5 + 1];
    float R2 = rois[n * 5 + 2];
    float R3 = rois[n * 5 + 3];
    float R4 = rois[n * 5 + 4];
    int b = (int)R0;
    float roi_sw = rintf(R1) * SPATIAL_SCALE - 0.5f;
    float roi_sh = rintf(R2) * SPATIAL_SCALE - 0.5f;
    float roi_ew = rintf(R3 + 1.0f) * SPATIAL_SCALE - 0.5f;
    float roi_eh = rintf(R4 + 1.0f) * SPATIAL_SCALE - 0.5f;
    float roi_w = fmaxf(roi_ew - roi_sw, 0.1f);
    float roi_h = fmaxf(roi_eh - roi_sh, 0.1f);
    float bin_w = roi_w * (1.0f / POOLED);
    float bin_h = roi_h * (1.0f / POOLED);
    float sub_w = bin_w * (1.0f / SAMPLES);
    float sub_h = bin_h * (1.0f / SAMPLES);

    for (int i = tid; i < NB * WIN * WIN; i += 512)
        ((float*)s_w)[i] = 0.0f;
    __syncthreads();

    // ---- plan: NB*16 <= 448 sample-tasks, single pass, 16-lane group per bin ----
    {
        int task = tid;
        bool inb = task < NB * NSAMP;
        int j  = task >> 4;
        int s  = task & 15;
        int jj = inb ? j : 0;
        int g  = binbase + jj;
        int ph = g / POOLED;
        int pw = g - ph * POOLED;

        float tx = offset[(n * 2 + 0) * NBIN + g] * TRANS_STD;
        float ty = offset[(n * 2 + 1) * NBIN + g] * TRANS_STD;
        float wstart = (float)pw * bin_w + roi_sw + tx * roi_w;
        float hstart = (float)ph * bin_h + roi_sh + ty * roi_h;

        float wlo = fminf(fmaxf(wstart, 0.0f), (float)WW - 1.0f);
        float hlo = fminf(fmaxf(hstart, 0.0f), (float)HH - 1.0f);
        int c0 = (int)floorf(wlo);
        int r0 = (int)floorf(hlo);

        int iy = s >> 2;
        int ix = s & 3;
        float h = hstart + (float)iy * sub_h;
        float w = wstart + (float)ix * sub_w;
        bool valid = inb & (w >= -0.5f) & (w <= (float)WW - 0.5f) &
                           (h >= -0.5f) & (h <= (float)HH - 0.5f);
        unsigned long long bal = __ballot(valid);
        int g16 = lane >> 4;
        int cnt = __popcll((bal >> (g16 * 16)) & 0xFFFFull);
        float sc = (cnt > 0) ? 1.0f / (float)cnt : 0.0f;

        if (valid) {
            float wc = fminf(fmaxf(w, 0.0f), (float)WW - 1.0f);
            float hc = fminf(fmaxf(h, 0.0f), (float)HH - 1.0f);
            float x0f = floorf(wc);
            float y0f = floorf(hc);
            int x0 = (int)x0f - c0;
            int y0 = (int)y0f - r0;
            int x1 = (int)ceilf(wc) - c0;
            int y1 = (int)ceilf(hc) - r0;
            float dx = wc - x0f;
            float dy = hc - y0f;
            atomicAdd(&s_w[j][y0 * WIN + x0], (1.0f - dx) * (1.0f - dy) * sc);
            atomicAdd(&s_w[j][y0 * WIN + x1], dx * (1.0f - dy) * sc);
            atomicAdd(&s_w[j][y1 * WIN + x0], (1.0f - dx) * dy * sc);
            atomicAdd(&s_w[j][y1 * WIN + x1], dx * dy * sc);
        }
        if (inb && s == 0) s_rc[j] = (r0 << 16) | c0;
    }
    __syncthreads();

    // ---- per-wave: compact + gather bins in PAIRS (j1, j1+8) ----
    const __hip_bfloat16* fbh = feat + (size_t)b * HWC + 2 * lane;

    for (int j1 = wv; j1 < NB; j1 += 16) {
        int j2 = j1 + 8;
        bool has2 = (j2 < NB);     // wave-uniform

        // compact j1
        float wa = (lane < WIN * WIN) ? s_w[j1][lane] : 0.0f;
        bool nza = (wa != 0.0f);
        unsigned long long bala = __ballot(nza);
        int cnta = __popcll(bala);
        {
            int rc = s_rc[j1];
            int r0 = rc >> 16, c0 = rc & 0xFFFF;
            if (nza) {
                int p = __popcll(bala & ((1ull << lane) - 1ull));
                int rr = lane / WIN;
                int cL = lane - rr * WIN;
                s_ow[j1][p] = make_int2(((r0 + rr) * WW + (c0 + cL)) * CC,
                                        __float_as_int(wa));
            }
        }
        // compact j2
        int cntb = 0;
        if (has2) {
            float wb = (lane < WIN * WIN) ? s_w[j2][lane] : 0.0f;
            bool nzb = (wb != 0.0f);
            unsigned long long balb = __ballot(nzb);
            cntb = __popcll(balb);
            int rc = s_rc[j2];
            int r0 = rc >> 16, c0 = rc & 0xFFFF;
            if (nzb) {
                int p = __popcll(balb & ((1ull << lane) - 1ull));
                int rr = lane / WIN;
                int cL = lane - rr * WIN;
                s_ow[j2][p] = make_int2(((r0 + rr) * WW + (c0 + cL)) * CC,
                                        __float_as_int(wb));
            }
        }
        int Pmax = ((max(cnta, cntb) + 7) & ~7);
        if (lane < Pmax) {
            if (lane >= cnta) s_ow[j1][lane] = make_int2(0, 0);
            if (has2 && lane >= cntb) s_ow[j2][lane] = make_int2(0, 0);
        }

        // gather: 16 loads in flight per iteration, bf16x2 = 2 channels/lane
        float axa = 0.0f, aya = 0.0f, axb = 0.0f, ayb = 0.0f;
        for (int i = 0; i < Pmax; i += 8) {
            unsigned va[8], vb[8];
            float fa[8], fb2[8];
            #pragma unroll
            for (int u = 0; u < 8; ++u) {
                int2 e = s_ow[j1][i + u];
                va[u] = *(const unsigned*)(fbh + e.x);
                fa[u] = __int_as_float(e.y);
            }
            if (has2) {
                #pragma unroll
                for (int u = 0; u < 8; ++u) {
                    int2 e = s_ow[j2][i + u];
                    vb[u] = *(const unsigned*)(fbh + e.x);
                    fb2[u] = __int_as_float(e.y);
                }
            }
            #pragma unroll
            for (int u = 0; u < 8; ++u) {
                axa += fa[u] * __uint_as_float(va[u] << 16);
                aya += fa[u] * __uint_as_float(va[u] & 0xFFFF0000u);
            }
            if (has2) {
                #pragma unroll
                for (int u = 0; u < 8; ++u) {
                    axb += fb2[u] * __uint_as_float(vb[u] << 16);
                    ayb += fb2[u] * __uint_as_float(vb[u] & 0xFFFF0000u);
                }
            }
        }
        s_res[(2 * lane + 0) * NBP + j1] = axa;
        s_res[(2 * lane + 1) * NBP + j1] = aya;
        if (has2) {
            s_res[(2 * lane + 0) * NBP + j2] = axb;
            s_res[(2 * lane + 1) * NBP + j2] = ayb;
        }
    }
    __syncthreads();

    // ---- write final (N,C,7,7) layout ----
    float* dst = out + (size_t)n * CC * NBIN + binbase;
    int c = tid >> 2;
    int part = tid & 3;
    int jj0 = part * 7;
    if (jj0 < NB) {
        #pragma unroll
        for (int k2 = 0; k2 < 7; ++k2)
            dst[c * NBIN + jj0 + k2] = s_res[c * NBP + jj0 + k2];
    }
}

// ---------------- fallback (no workspace): direct CHW f32 ----------------
__global__ __launch_bounds__(128) void dpsroi_fallback(
        const float* __restrict__ feat,
        const float* __restrict__ rois,
        const float* __restrict__ offset,
        float* __restrict__ out, int N) {
    int bin = blockIdx.x;
    int pw = bin % POOLED;
    int ph = (bin / POOLED) % POOLED;
    int n  = bin / NBIN;
    int c  = threadIdx.x;
    float R1 = rois[n * 5 + 1], R2 = rois[n * 5 + 2];
    float R3 = rois[n * 5 + 3], R4 = rois[n * 5 + 4];
    int b = (int)rois[n * 5 + 0];
    float roi_sw = rintf(R1) * SPATIAL_SCALE - 0.5f;
    float roi_sh = rintf(R2) * SPATIAL_SCALE - 0.5f;
    float roi_ew = rintf(R3 + 1.0f) * SPATIAL_SCALE - 0.5f;
    float roi_eh = rintf(R4 + 1.0f) * SPATIAL_SCALE - 0.5f;
    float roi_w = fmaxf(roi_ew - roi_sw, 0.1f);
    float roi_h = fmaxf(roi_eh - roi_sh, 0.1f);
    float bin_w = roi_w / POOLED, bin_h = roi_h / POOLED;
    float sub_w = bin_w / SAMPLES, sub_h = bin_h / SAMPLES;
    float tx = offset[((n * 2 + 0) * PARTS + ph) * PARTS + pw] * TRANS_STD;
    float ty = offset[((n * 2 + 1) * PARTS + ph) * PARTS + pw] * TRANS_STD;
    float wstart = (float)pw * bin_w + roi_sw + tx * roi_w;
    float hstart = (float)ph * bin_h + roi_sh + ty * roi_h;
    const float* fb = feat + ((size_t)b * CC + c) * HH * WW;
    float s = 0.0f; int cnt = 0;
    for (int iy = 0; iy < SAMPLES; ++iy) {
        float h = hstart + iy * sub_h;
        for (int ix = 0; ix < SAMPLES; ++ix) {
            float w = wstart + ix * sub_w;
            if (!((w >= -0.5f) & (w <= WW - 0.5f) & (h >= -0.5f) & (h <= HH - 0.5f)))
                continue;
            float wc = fminf(fmaxf(w, 0.0f), WW - 1.0f);
            float hc = fminf(fmaxf(h, 0.0f), HH - 1.0f);
            float x0f = floorf(wc), y0f = floorf(hc);
            int x0 = (int)x0f, y0 = (int)y0f;
            int x1 = (int)ceilf(wc), y1 = (int)ceilf(hc);
            float dx = wc - x0f, dy = hc - y0f;
            s += (1 - dx) * (1 - dy) * fb[y0 * WW + x0] + dx * (1 - dy) * fb[y0 * WW + x1]
               + (1 - dx) * dy * fb[y1 * WW + x0] + dx * dy * fb[y1 * WW + x1];
            cnt++;
        }
    }
    out[(((size_t)n * CC + c) * POOLED + ph) * POOLED + pw] =
        cnt > 0 ? s / (float)cnt : 0.0f;
}

extern "C" void kernel_launch(void* const* d_in, const int* in_sizes, int n_in,
                              void* d_out, int out_size, void* d_ws, size_t ws_size,
                              hipStream_t stream) {
    const float* data   = (const float*)d_in[0];
    const float* rois   = (const float*)d_in[1];
    const float* offset = (const float*)d_in[2];
    float* out = (float*)d_out;
    int N = in_sizes[1] / 5;

    size_t feat_bytes = (size_t)BB * CC * HH * WW * sizeof(__hip_bfloat16);
    feat_bytes = (feat_bytes + 255) & ~(size_t)255;
    size_t perm_bytes = (size_t)N * sizeof(int);
    int nbins = N * NBIN;

    if (ws_size >= feat_bytes + perm_bytes) {
        __hip_bfloat16* featT = (__hip_bfloat16*)d_ws;
        int* perm = (int*)((char*)d_ws + feat_bytes);
        dim3 tgrid(HH * WW / 128, BB);
        hipLaunchKernelGGL(transpose_csort, tgrid, dim3(256), 0, stream,
                           data, featT, rois, N, perm);
        hipLaunchKernelGGL(dpsroi_half, dim3(2 * N), dim3(512), 0, stream,
                           featT, rois, offset, perm, out, N);
    } else {
        hipLaunchKernelGGL(dpsroi_fallback, dim3(nbins), dim3(CC), 0, stream,
                           data, rois, offset, out, N);
    }
}

// Round 14
// 34.377 us; speedup vs baseline: 1.1602x; 1.1602x over previous
//
#include <hip/hip_runtime.h>
#include <hip/hip_bf16.h>

#define SPATIAL_SCALE 0.0625f
#define POOLED 7
#define NBIN 49
#define PARTS 7
#define SAMPLES 4
#define NSAMP 16
#define TRANS_STD 0.1f

#define BB 2
#define CC 128
#define HH 128
#define WW 128
#define HWC (HH * WW * CC)    // elements

#define WIN 5        // max window extent per axis (3*sub_w <= 2.91)
#define MAXP 32      // 25 cells padded
#define NKEY 128     // BB * 8 * 8 spatial-cell keys

// ---------------- fused: transpose (B,C,H,W)f32 -> (B,H,W,C)bf16  +  csort ----------------
// PRODUCER-CONSUMER XCD ALIGNMENT: 1D grid, 256 blocks. Assuming round-robin
// block->XCD (id & 7), XCD x transposes the band (batch = x>>2,
// rows [32*(x&3), +32)) -- exactly the band whose ROIs the pool's csort +
// chunk-swizzle assigns to pool-XCD x. Freshly-written featT lines are then
// DIRTY IN THE LOCAL L2 when the pool reads them (halo only goes remote).
__global__ __launch_bounds__(256) void transpose_csort(
        const float* __restrict__ in, __hip_bfloat16* __restrict__ out,
        const float* __restrict__ rois, int N, int* __restrict__ perm) {
    __shared__ float tile[128][129];
    __shared__ int hist[NKEY];
    __shared__ int scan[NKEY];
    __shared__ int pos[NKEY];

    int tid = threadIdx.x;
    int id  = blockIdx.x;

    if (id == 0) {
        // ---- counting sort of ROIs by (batch, 8x8 cell) ----
        if (tid < NKEY) hist[tid] = 0;
        __syncthreads();
        for (int i = tid; i < N; i += 256) {
            float b  = rois[i * 5 + 0];
            float x1 = rois[i * 5 + 1];
            float y1 = rois[i * 5 + 2];
            float x2 = rois[i * 5 + 3];
            float y2 = rois[i * 5 + 4];
            float fx = (x1 + x2) * 0.5f * SPATIAL_SCALE;
            float fy = (y1 + y2) * 0.5f * SPATIAL_SCALE;
            int cx = min(7, max(0, (int)(fx * 0.0625f)));
            int cy = min(7, max(0, (int)(fy * 0.0625f)));
            atomicAdd(&hist[((int)b * 8 + cy) * 8 + cx], 1);
        }
        __syncthreads();
        if (tid < NKEY) scan[tid] = hist[tid];
        __syncthreads();
        #pragma unroll
        for (int s = 1; s < NKEY; s <<= 1) {
            int v = 0;
            if (tid < NKEY && tid >= s) v = scan[tid - s];
            __syncthreads();
            if (tid < NKEY) scan[tid] += v;
            __syncthreads();
        }
        if (tid < NKEY) pos[tid] = scan[tid] - hist[tid];
        __syncthreads();
        for (int i = tid; i < N; i += 256) {
            float b  = rois[i * 5 + 0];
            float x1 = rois[i * 5 + 1];
            float y1 = rois[i * 5 + 2];
            float x2 = rois[i * 5 + 3];
            float y2 = rois[i * 5 + 4];
            float fx = (x1 + x2) * 0.5f * SPATIAL_SCALE;
            float fy = (y1 + y2) * 0.5f * SPATIAL_SCALE;
            int cx = min(7, max(0, (int)(fx * 0.0625f)));
            int cy = min(7, max(0, (int)(fy * 0.0625f)));
            int key = ((int)b * 8 + cy) * 8 + cx;
            int slot = atomicAdd(&pos[key], 1);
            perm[slot] = i;
        }
        __syncthreads();
    }

    // ---- XCD-aligned strip assignment ----
    int xcd = id & 7;
    int k   = id >> 3;               // 0..31
    int bt  = xcd >> 2;              // batch handled by this XCD
    int row = 32 * (xcd & 3) + k;    // row within [32*(xcd&3), +32)

    const int HW = HH * WW;
    size_t base = (size_t)bt * CC * HW;
    int p0 = row * WW;               // 128-position strip = one image row

    #pragma unroll
    for (int it = 0; it < 16; ++it) {
        int i = tid + it * 256;        // 0..4095
        int c = i >> 5;                // channel
        int q = i & 31;                // float4 index within row
        float4 v = *(const float4*)(in + base + (size_t)c * HW + p0 + 4 * q);
        int p = 4 * q;
        tile[p + 0][c] = v.x;
        tile[p + 1][c] = v.y;
        tile[p + 2][c] = v.z;
        tile[p + 3][c] = v.w;
    }
    __syncthreads();

    __hip_bfloat16* dst = out + base + (size_t)p0 * CC;
    #pragma unroll
    for (int it = 0; it < 16; ++it) {
        int i = tid + it * 256;
        int p = i >> 5;
        int m = i & 31;                // channel quad
        union { ushort4 u4; __hip_bfloat16 h[4]; } pk;
        pk.h[0] = __float2bfloat16(tile[p][4 * m + 0]);
        pk.h[1] = __float2bfloat16(tile[p][4 * m + 1]);
        pk.h[2] = __float2bfloat16(tile[p][4 * m + 2]);
        pk.h[3] = __float2bfloat16(tile[p][4 * m + 3]);
        *(ushort4*)(dst + (size_t)p * CC + 4 * m) = pk.u4;
    }
}

// ---------------- one ROI per block; paired-bin gather (r8, proven best) ----------------
__global__ __launch_bounds__(512) void dpsroi_roi2(
        const __hip_bfloat16* __restrict__ feat,   // (B,H,W,C) bf16
        const float* __restrict__ rois,
        const float* __restrict__ offset,
        const int* __restrict__ perm,
        float* __restrict__ out,                   // (N, C, 7, 7) f32
        int N) {
    __shared__ float s_w[NBIN][WIN * WIN];
    __shared__ int2  s_ow[NBIN][MAXP];
    __shared__ int   s_rc[NBIN];
    __shared__ float s_res[CC * NBIN];

    int tid  = threadIdx.x;
    int lane = tid & 63;
    int wv   = tid >> 6;

    // bijective XCD chunk swizzle over the N ROI-blocks (m204)
    int nwg = gridDim.x;
    int q = nwg >> 3, r = nwg & 7;
    int xcd = blockIdx.x & 7;
    int idx = blockIdx.x >> 3;
    int wg = (xcd < r ? xcd * (q + 1) : r * (q + 1) + (xcd - r) * q) + idx;
    int n = perm[wg];

    float R0 = rois[n * 5 + 0];
    float R1 = rois[n * 5 + 1];
    float R2 = rois[n * 5 + 2];
    float R3 = rois[n * 5 + 3];
    float R4 = rois[n * 5 + 4];
    int b = (int)R0;
    float roi_sw = rintf(R1) * SPATIAL_SCALE - 0.5f;
    float roi_sh = rintf(R2) * SPATIAL_SCALE - 0.5f;
    float roi_ew = rintf(R3 + 1.0f) * SPATIAL_SCALE - 0.5f;
    float roi_eh = rintf(R4 + 1.0f) * SPATIAL_SCALE - 0.5f;
    float roi_w = fmaxf(roi_ew - roi_sw, 0.1f);
    float roi_h = fmaxf(roi_eh - roi_sh, 0.1f);
    float bin_w = roi_w * (1.0f / POOLED);
    float bin_h = roi_h * (1.0f / POOLED);
    float sub_w = bin_w * (1.0f / SAMPLES);
    float sub_h = bin_h * (1.0f / SAMPLES);

    for (int i = tid; i < NBIN * WIN * WIN; i += 512)
        ((float*)s_w)[i] = 0.0f;
    __syncthreads();

    // ---- plan: 784 sample-tasks, 16-lane group per bin ----
    #pragma unroll
    for (int it = 0; it < 2; ++it) {
        int task = tid + it * 512;
        bool inb = task < NBIN * NSAMP;
        int j  = task >> 4;
        int s  = task & 15;
        int jj = inb ? j : 0;
        int ph = jj / POOLED;
        int pw = jj - ph * POOLED;

        float tx = offset[(n * 2 + 0) * NBIN + jj] * TRANS_STD;
        float ty = offset[(n * 2 + 1) * NBIN + jj] * TRANS_STD;
        float wstart = (float)pw * bin_w + roi_sw + tx * roi_w;
        float hstart = (float)ph * bin_h + roi_sh + ty * roi_h;

        float wlo = fminf(fmaxf(wstart, 0.0f), (float)WW - 1.0f);
        float hlo = fminf(fmaxf(hstart, 0.0f), (float)HH - 1.0f);
        int c0 = (int)floorf(wlo);
        int r0 = (int)floorf(hlo);

        int iy = s >> 2;
        int ix = s & 3;
        float h = hstart + (float)iy * sub_h;
        float w = wstart + (float)ix * sub_w;
        bool valid = inb & (w >= -0.5f) & (w <= (float)WW - 0.5f) &
                           (h >= -0.5f) & (h <= (float)HH - 0.5f);
        unsigned long long bal = __ballot(valid);
        int g = lane >> 4;
        int cnt = __popcll((bal >> (g * 16)) & 0xFFFFull);
        float sc = (cnt > 0) ? 1.0f / (float)cnt : 0.0f;

        if (valid) {
            float wc = fminf(fmaxf(w, 0.0f), (float)WW - 1.0f);
            float hc = fminf(fmaxf(h, 0.0f), (float)HH - 1.0f);
            float x0f = floorf(wc);
            float y0f = floorf(hc);
            int x0 = (int)x0f - c0;
            int y0 = (int)y0f - r0;
            int x1 = (int)ceilf(wc) - c0;
            int y1 = (int)ceilf(hc) - r0;
            float dx = wc - x0f;
            float dy = hc - y0f;
            atomicAdd(&s_w[j][y0 * WIN + x0], (1.0f - dx) * (1.0f - dy) * sc);
            atomicAdd(&s_w[j][y0 * WIN + x1], dx * (1.0f - dy) * sc);
            atomicAdd(&s_w[j][y1 * WIN + x0], (1.0f - dx) * dy * sc);
            atomicAdd(&s_w[j][y1 * WIN + x1], dx * dy * sc);
        }
        if (inb && s == 0) s_rc[j] = (r0 << 16) | c0;
    }
    __syncthreads();

    // ---- per-wave: compact + gather bins in PAIRS (j1, j1+8) ----
    const __hip_bfloat16* fbh = feat + (size_t)b * HWC + 2 * lane;

    for (int j1 = wv; j1 < NBIN; j1 += 16) {
        int j2 = j1 + 8;
        bool has2 = (j2 < NBIN);     // wave-uniform

        // compact j1
        float wa = (lane < WIN * WIN) ? s_w[j1][lane] : 0.0f;
        bool nza = (wa != 0.0f);
        unsigned long long bala = __ballot(nza);
        int cnta = __popcll(bala);
        {
            int rc = s_rc[j1];
            int r0 = rc >> 16, c0 = rc & 0xFFFF;
            if (nza) {
                int p = __popcll(bala & ((1ull << lane) - 1ull));
                int rr = lane / WIN;
                int cL = lane - rr * WIN;
                s_ow[j1][p] = make_int2(((r0 + rr) * WW + (c0 + cL)) * CC,
                                        __float_as_int(wa));
            }
        }
        // compact j2
        int cntb = 0;
        if (has2) {
            float wb = (lane < WIN * WIN) ? s_w[j2][lane] : 0.0f;
            bool nzb = (wb != 0.0f);
            unsigned long long balb = __ballot(nzb);
            cntb = __popcll(balb);
            int rc = s_rc[j2];
            int r0 = rc >> 16, c0 = rc & 0xFFFF;
            if (nzb) {
                int p = __popcll(balb & ((1ull << lane) - 1ull));
                int rr = lane / WIN;
                int cL = lane - rr * WIN;
                s_ow[j2][p] = make_int2(((r0 + rr) * WW + (c0 + cL)) * CC,
                                        __float_as_int(wb));
            }
        }
        int Pmax = ((max(cnta, cntb) + 7) & ~7);
        if (lane < Pmax) {
            if (lane >= cnta) s_ow[j1][lane] = make_int2(0, 0);
            if (has2 && lane >= cntb) s_ow[j2][lane] = make_int2(0, 0);
        }

        // gather: 16 loads in flight per iteration
        float axa = 0.0f, aya = 0.0f, axb = 0.0f, ayb = 0.0f;
        for (int i = 0; i < Pmax; i += 8) {
            unsigned va[8], vb[8];
            float fa[8], fb2[8];
            #pragma unroll
            for (int u = 0; u < 8; ++u) {
                int2 e = s_ow[j1][i + u];
                va[u] = *(const unsigned*)(fbh + e.x);
                fa[u] = __int_as_float(e.y);
            }
            if (has2) {
                #pragma unroll
                for (int u = 0; u < 8; ++u) {
                    int2 e = s_ow[j2][i + u];
                    vb[u] = *(const unsigned*)(fbh + e.x);
                    fb2[u] = __int_as_float(e.y);
                }
            }
            #pragma unroll
            for (int u = 0; u < 8; ++u) {
                axa += fa[u] * __uint_as_float(va[u] << 16);
                aya += fa[u] * __uint_as_float(va[u] & 0xFFFF0000u);
            }
            if (has2) {
                #pragma unroll
                for (int u = 0; u < 8; ++u) {
                    axb += fb2[u] * __uint_as_float(vb[u] << 16);
                    ayb += fb2[u] * __uint_as_float(vb[u] & 0xFFFF0000u);
                }
            }
        }
        s_res[(2 * lane + 0) * NBIN + j1] = axa;
        s_res[(2 * lane + 1) * NBIN + j1] = aya;
        if (has2) {
            s_res[(2 * lane + 0) * NBIN + j2] = axb;
            s_res[(2 * lane + 1) * NBIN + j2] = ayb;
        }
    }
    __syncthreads();

    // ---- write final (N,C,7,7) layout, fully coalesced ----
    float* dst = out + (size_t)n * CC * NBIN;
    for (int i = tid; i < CC * NBIN; i += 512) {
        dst[i] = s_res[i];
    }
}

// ---------------- fallback (no workspace): direct CHW f32 ----------------
__global__ __launch_bounds__(128) void dpsroi_fallback(
        const float* __restrict__ feat,
        const float* __restrict__ rois,
        const float* __restrict__ offset,
        float* __restrict__ out, int N) {
    int bin = blockIdx.x;
    int pw = bin % POOLED;
    int ph = (bin / POOLED) % POOLED;
    int n  = bin / NBIN;
    int c  = threadIdx.x;
    float R1 = rois[n * 5 + 1], R2 = rois[n * 5 + 2];
    float R3 = rois[n * 5 + 3], R4 = rois[n * 5 + 4];
    int b = (int)rois[n * 5 + 0];
    float roi_sw = rintf(R1) * SPATIAL_SCALE - 0.5f;
    float roi_sh = rintf(R2) * SPATIAL_SCALE - 0.5f;
    float roi_ew = rintf(R3 + 1.0f) * SPATIAL_SCALE - 0.5f;
    float roi_eh = rintf(R4 + 1.0f) * SPATIAL_SCALE - 0.5f;
    float roi_w = fmaxf(roi_ew - roi_sw, 0.1f);
    float roi_h = fmaxf(roi_eh - roi_sh, 0.1f);
    float bin_w = roi_w / POOLED, bin_h = roi_h / POOLED;
    float sub_w = bin_w / SAMPLES, sub_h = bin_h / SAMPLES;
    float tx = offset[((n * 2 + 0) * PARTS + ph) * PARTS + pw] * TRANS_STD;
    float ty = offset[((n * 2 + 1) * PARTS + ph) * PARTS + pw] * TRANS_STD;
    float wstart = (float)pw * bin_w + roi_sw + tx * roi_w;
    float hstart = (float)ph * bin_h + roi_sh + ty * roi_h;
    const float* fb = feat + ((size_t)b * CC + c) * HH * WW;
    float s = 0.0f; int cnt = 0;
    for (int iy = 0; iy < SAMPLES; ++iy) {
        float h = hstart + iy * sub_h;
        for (int ix = 0; ix < SAMPLES; ++ix) {
            float w = wstart + ix * sub_w;
            if (!((w >= -0.5f) & (w <= WW - 0.5f) & (h >= -0.5f) & (h <= HH - 0.5f)))
                continue;
            float wc = fminf(fmaxf(w, 0.0f), WW - 1.0f);
            float hc = fminf(fmaxf(h, 0.0f), HH - 1.0f);
            float x0f = floorf(wc), y0f = floorf(hc);
            int x0 = (int)x0f, y0 = (int)y0f;
            int x1 = (int)ceilf(wc), y1 = (int)ceilf(hc);
            float dx = wc - x0f, dy = hc - y0f;
            s += (1 - dx) * (1 - dy) * fb[y0 * WW + x0] + dx * (1 - dy) * fb[y0 * WW + x1]
               + (1 - dx) * dy * fb[y1 * WW + x0] + dx * dy * fb[y1 * WW + x1];
            cnt++;
        }
    }
    out[(((size_t)n * CC + c) * POOLED + ph) * POOLED + pw] =
        cnt > 0 ? s / (float)cnt : 0.0f;
}

extern "C" void kernel_launch(void* const* d_in, const int* in_sizes, int n_in,
                              void* d_out, int out_size, void* d_ws, size_t ws_size,
                              hipStream_t stream) {
    const float* data   = (const float*)d_in[0];
    const float* rois   = (const float*)d_in[1];
    const float* offset = (const float*)d_in[2];
    float* out = (float*)d_out;
    int N = in_sizes[1] / 5;

    size_t feat_bytes = (size_t)BB * CC * HH * WW * sizeof(__hip_bfloat16);
    feat_bytes = (feat_bytes + 255) & ~(size_t)255;
    size_t perm_bytes = (size_t)N * sizeof(int);
    int nbins = N * NBIN;

    if (ws_size >= feat_bytes + perm_bytes) {
        __hip_bfloat16* featT = (__hip_bfloat16*)d_ws;
        int* perm = (int*)((char*)d_ws + feat_bytes);
        hipLaunchKernelGGL(transpose_csort, dim3(BB * HH), dim3(256), 0, stream,
                           data, featT, rois, N, perm);
        hipLaunchKernelGGL(dpsroi_roi2, dim3(N), dim3(512), 0, stream,
                           featT, rois, offset, perm, out, N);
    } else {
        hipLaunchKernelGGL(dpsroi_fallback, dim3(nbins), dim3(CC), 0, stream,
                           data, rois, offset, out, N);
    }
}